// Round 4
// baseline (238.419 us; speedup 1.0000x reference)
//
#include <hip/hip_runtime.h>

// Forward-fill imputation (SIMPLE.imputate), fused single-kernel, MLP-deep.
//   observed = mask < 0.9
//   gather_idx[b,n] = most recent observed pos <= n (wrap-around to row's last
//                     observed for leading missing; 0 if row has none)
//   out[b,n,:] = in[b, gather_idx[b,n], :]
//
// B=64, N=4096, D=128 fp32. ~134MB write + ~121MB read -> ~39us HBM roofline.
// Round-2 fused version was latency-bound (16 barriers, VGPR=32, 2.4TB/s).
// Round-3 split version fixed MLP but pays a gidx HBM round-trip + 2nd launch.
// This version fuses with the GOOD structure: shfl-based scan (2 barriers
// total), slice indices in LDS, then 16 independent float4 loads per thread
// (64 data VGPRs in flight) + nontemporal stores. No workspace use.

#define FF_N 4096
#define FF_D 128
#define SLICES 32                 // blocks per batch row
#define SLICE_N (FF_N / SLICES)   // 128 (b,n) rows per block

typedef float f4 __attribute__((ext_vector_type(4)));

__global__ __launch_bounds__(256) void ffill_fused(const f4* __restrict__ in,
                                                   const float* __restrict__ mask,
                                                   f4* __restrict__ out) {
    const int b   = blockIdx.x >> 5;   // batch row
    const int s   = blockIdx.x & 31;   // slice within row
    const int tid = threadIdx.x;

    __shared__ int wmax[4];            // per-wave maxima
    __shared__ int gslice[SLICE_N];    // resolved gather idx for MY slice

    // ---- Phase A: redundant per-row scan (mask row is 16KB, L2-resident) ----
    const float* m = mask + (size_t)b * FF_N;
    const int base = tid * 16;

    float4 mv[4];
    const float4* m4 = reinterpret_cast<const float4*>(m + base);
#pragma unroll
    for (int k = 0; k < 4; ++k) mv[k] = m4[k];

    unsigned obsbits = 0;
    int segmax = -1;
#pragma unroll
    for (int k = 0; k < 4; ++k) {
        const float vals[4] = {mv[k].x, mv[k].y, mv[k].z, mv[k].w};
#pragma unroll
        for (int j = 0; j < 4; ++j) {
            const int idx = k * 4 + j;
            const bool o = vals[j] < 0.9f;     // observed
            obsbits |= (unsigned)o << idx;
            if (o) segmax = base + idx;
        }
    }

    // Wave-level inclusive max-scan (no barriers).
    const int lane = tid & 63;
    int incl = segmax;
#pragma unroll
    for (int off = 1; off < 64; off <<= 1) {
        const int t = __shfl_up(incl, off, 64);
        if (lane >= off) incl = max(incl, t);
    }

    // Cross-wave combine (barrier #1).
    if (lane == 63) wmax[tid >> 6] = incl;
    __syncthreads();
    const int wid = tid >> 6;
    int wpre = -1, total = -1;
#pragma unroll
    for (int w = 0; w < 4; ++w) {
        const int x = wmax[w];
        total = max(total, x);
        if (w < wid) wpre = max(wpre, x);
    }
    const int inclp  = __shfl_up(incl, 1, 64);
    const int prefix = max(wpre, (lane == 0) ? -1 : inclp);  // exclusive prefix
    const int fallback = (total < 0) ? 0 : total;            // empty row -> 0

    // Forward fill my 16 elements; only the 8 threads owning this block's
    // slice ([s*128, s*128+128)) publish to LDS.
    int last = prefix;
    int outv[16];
#pragma unroll
    for (int k = 0; k < 16; ++k) {
        if ((obsbits >> k) & 1u) last = base + k;
        outv[k] = (last < 0) ? fallback : last;
    }
    if ((tid >> 3) == s) {
        int4* g4 = reinterpret_cast<int4*>(&gslice[(tid & 7) * 16]);
#pragma unroll
        for (int k = 0; k < 4; ++k)
            g4[k] = make_int4(outv[4 * k], outv[4 * k + 1],
                              outv[4 * k + 2], outv[4 * k + 3]);
    }
    __syncthreads();                   // barrier #2

    // ---- Phase B: 16 independent gathers per thread, NT stores ----
    const int l    = tid & 31;         // float4 lane within D (32 per row)
    const int rsub = tid >> 5;         // 0..7
    const f4* inb = in + (size_t)b * FF_N * (FF_D / 4);

    int gi[16];
#pragma unroll
    for (int i = 0; i < 16; ++i) gi[i] = gslice[i * 8 + rsub];  // LDS broadcast

    f4 v[16];
#pragma unroll
    for (int i = 0; i < 16; ++i)
        v[i] = inb[(size_t)gi[i] * (FF_D / 4) + l];

    f4* outb = out + ((size_t)b * FF_N + (size_t)s * SLICE_N) * (FF_D / 4);
#pragma unroll
    for (int i = 0; i < 16; ++i)
        __builtin_nontemporal_store(v[i], &outb[i * 256 + tid]);
}

extern "C" void kernel_launch(void* const* d_in, const int* in_sizes, int n_in,
                              void* d_out, int out_size, void* d_ws, size_t ws_size,
                              hipStream_t stream) {
    const float* inp  = (const float*)d_in[0];   // [B, N, D] fp32
    const float* mask = (const float*)d_in[1];   // [B, N]    fp32
    f4* out = (f4*)d_out;

    const int B = in_sizes[1] / FF_N;            // 64
    ffill_fused<<<B * SLICES, 256, 0, stream>>>(
        (const f4*)inp, mask, out);
}